// Round 10
// baseline (3331.487 us; speedup 1.0000x reference)
//
#include <hip/hip_runtime.h>
#include <hip/hip_bf16.h>
#include <math.h>

// ---------------------------------------------------------------------------
// LSTM text classifier forward, MI355X/gfx950.  Round 10.
//
// R9 post-mortem: 8-wave structure is arithmetically over budget: demand
// ~132 VGPR vs 128 available (256/wave at 2 waves/SIMD minus 128 AGPR).
// Fences can't fix a deficit; opaque "+v" pointer hacks added VALU address
// math (65% VALUBusy/CU). VGPR pegged at 128 both rounds -> scratch spill.
//
// R10: 4 waves x 1 wave/SIMD (__launch_bounds__(256,1)) = 512 regs/wave.
//   Wave w owns unit-tiles {4w..4w+3}:
//     tiles 4w,4w+1: U in AGPR  (64 frags = 256 AGPRs, proven "+a" pin)
//     tile  4w+2:    U in LDS   (4 waves x 32 KB = 128 KB, ds_read_b128)
//     tile  4w+3:    U streamed from L2 (32 frags/step, depth-4 pipeline
//                    of 4-frag groups; <=80 stream regs live)
//   Worst-point VGPR ~230 < 256 -> real slack. No opaque pointer asm;
//   cross-iteration hoist blocked by asm volatile("":::"memory") at loop
//   top (inert) + sched_barrier(0) stage fences. Arithmetic identical to
//   R7/R9 (absmax 2.44e-4). Checkpoint: VGPR_Count not pegged (<256).
//
// Grid: 4 blocks x 256 thr, zero inter-block comm; block g = batches
// 16g..16g+16, full 256-unit update; h dbl-buffered in LDS; c in regs.
//
// MFMA 16x16x32 bf16 layouts (m89/m91):
//   A[m][k]: m=lane&15, k=(lane>>4)*8+j      B[k][n]: n=lane&15, same k
//   C/D:     col=lane&15, row=(lane>>4)*4+reg
// ---------------------------------------------------------------------------

typedef __bf16 bf16_t;
typedef bf16_t bf16x8 __attribute__((ext_vector_type(8)));
typedef bf16_t bf16x4 __attribute__((ext_vector_type(4)));
typedef float  f32x4  __attribute__((ext_vector_type(4)));

#define T_SZ 512
#define HID 256
#define G4 1024
#define NCLS 20

// workspace layout (bytes)
#define WS_UPACK 0u
#define WS_WPACK (512u * 1024u)
#define WS_HFIN  (1024u * 1024u)                  // 64 KB
#define WS_XZ    (2u * 1024u * 1024u)             // 64 MB
// total: 66 MB

// ---------------------------------------------------------------------------
// Pack W and U (f32 [256][1024]) into bf16 B-fragment order:
// frag f = (ntile*8 + kstep)*64 + lane ; element j=0..7
// value = M[kstep*32 + (lane>>4)*8 + j][ntile*16 + (lane&15)]
// ---------------------------------------------------------------------------
__global__ void pack_weights(const float* __restrict__ W, const float* __restrict__ U,
                             bf16_t* __restrict__ Wp, bf16_t* __restrict__ Up) {
    int tid  = blockIdx.x * blockDim.x + threadIdx.x;   // 0..262143
    int j    = tid & 7;
    int lane = (tid >> 3) & 63;
    int ks   = (tid >> 9) & 7;
    int nt   = tid >> 12;
    int row  = ks * 32 + ((lane >> 4) << 3) + j;
    int col  = nt * 16 + (lane & 15);
    Wp[tid] = (bf16_t)W[row * G4 + col];
    Up[tid] = (bf16_t)U[row * G4 + col];
}

// ---------------------------------------------------------------------------
// Phase A: xz = emb[x] @ W + bias, stored bf16 in C-fragment order:
//   xz2[((t*4 + bchunk)*64 + ntile)*64 + lane] = bf16x4 {r=0..3}
// value[r] = z[batch = bchunk*16 + (lane>>4)*4 + r][col = ntile*16 + (lane&15)]
// ---------------------------------------------------------------------------
__global__ __launch_bounds__(256) void xz_gemm(const int* __restrict__ x,
                                               const float* __restrict__ emb,
                                               const bf16_t* __restrict__ Wp,
                                               const float* __restrict__ bias,
                                               bf16x4* __restrict__ xz2) {
    int nb   = blockIdx.x & 7;
    int t    = blockIdx.x >> 3;
    int w    = threadIdx.x >> 6;
    int lane = threadIdx.x & 63;
    int l15  = lane & 15;
    int quad = lane >> 4;

    int b_row = w * 16 + l15;
    int tok   = x[b_row * T_SZ + t];
    const float* erow = emb + (size_t)tok * 256;

    bf16x8 afrag[8];
#pragma unroll
    for (int ks = 0; ks < 8; ks++) {
        const float4* p = (const float4*)(erow + ks * 32 + quad * 8);
        float4 v0 = p[0], v1 = p[1];
        bf16x8 a;
        a[0] = (bf16_t)v0.x; a[1] = (bf16_t)v0.y; a[2] = (bf16_t)v0.z; a[3] = (bf16_t)v0.w;
        a[4] = (bf16_t)v1.x; a[5] = (bf16_t)v1.y; a[6] = (bf16_t)v1.z; a[7] = (bf16_t)v1.w;
        afrag[ks] = a;
    }

    const bf16x8* Wf = (const bf16x8*)Wp;

#pragma unroll
    for (int nt = 0; nt < 8; nt++) {
        int ntg = nb * 8 + nt;
        float bv = bias[ntg * 16 + l15];
        f32x4 acc = {bv, bv, bv, bv};
        const bf16x8* bp = Wf + (size_t)(ntg * 8) * 64 + lane;
#pragma unroll
        for (int ks = 0; ks < 8; ks++) {
            bf16x8 bfrag = bp[ks * 64];
            acc = __builtin_amdgcn_mfma_f32_16x16x32_bf16(afrag[ks], bfrag, acc, 0, 0, 0);
        }
        bf16x4 hv;
#pragma unroll
        for (int r = 0; r < 4; r++) hv[r] = (bf16_t)acc[r];
        xz2[((size_t)(t * 4 + w) * 64 + ntg) * 64 + lane] = hv;
    }
}

__device__ __forceinline__ float sigmoid_f(float z) {
    return 1.0f / (1.0f + __expf(-z));
}
__device__ __forceinline__ float tanh_f(float z) {
    float e = __expf(2.0f * z);
    return 1.0f - 2.0f / (e + 1.0f);
}

// MFMA with B operand in AGPR class (gfx950 unified file; proven R5-R9).
__device__ __forceinline__ void mfma_aB(f32x4& d, bf16x8 a, bf16x8 b) {
    asm("v_mfma_f32_16x16x32_bf16 %0, %1, %2, %0" : "+v"(d) : "v"(a), "a"(b));
}

#define PIN8(A) asm volatile("" : "+a"(A[0]), "+a"(A[1]), "+a"(A[2]), "+a"(A[3]), \
                                   "+a"(A[4]), "+a"(A[5]), "+a"(A[6]), "+a"(A[7]))

// ---------------------------------------------------------------------------
// Phase B: recurrence. Grid: 4 blocks x 256 thr (4 waves, 1/SIMD).
// Wave w: tiles 4w,4w+1 AGPR-U; 4w+2 LDS-U; 4w+3 L2-streamed.
// ---------------------------------------------------------------------------
__global__ __launch_bounds__(256, 1) void lstm_v4(const bf16x4* __restrict__ xz2,
                                                  const bf16_t* __restrict__ Up,
                                                  float* __restrict__ hfin) {
    __shared__ bf16x8 ulds[128 * 64];                  // 128 KB: tile 4w+2
    __shared__ __align__(16) bf16_t h_lds[2][16][264]; // 16.9 KB dbl-buffered

    const int g    = blockIdx.x;
    const int w    = threadIdx.x >> 6;
    const int lane = threadIdx.x & 63;
    const int l15  = lane & 15;
    const int quad = lane >> 4;
    const int ntS  = 4 * w + 3;                        // streamed tile

    const bf16x8* Uf  = (const bf16x8*)Up + lane;
    const bf16x8* Ufr = (const bf16x8*)Up;

    // ---- tiles 4w, 4w+1 -> AGPRs (once): 64 frags = 256 AGPRs --------------
    bf16x8 uA[2][4][8];
#pragma unroll
    for (int tt = 0; tt < 2; tt++)
#pragma unroll
        for (int G = 0; G < 4; G++)
#pragma unroll
            for (int ks = 0; ks < 8; ks++)
                uA[tt][G][ks] = Uf[((G * 16 + 4 * w + tt) * 8 + ks) * 64];
    PIN8(uA[0][0]); PIN8(uA[0][1]); PIN8(uA[0][2]); PIN8(uA[0][3]);
    PIN8(uA[1][0]); PIN8(uA[1][1]); PIN8(uA[1][2]); PIN8(uA[1][3]);

    // ---- tile 4w+2 -> LDS (once); frag fi = w*32 + G*8 + ks ----------------
    for (int i = threadIdx.x; i < 128 * 64; i += 256) {
        int fi = i >> 6, ln = i & 63;
        int w2 = fi >> 5, G = (fi >> 3) & 3, ks = fi & 7;
        ulds[i] = Ufr[((G * 16 + 4 * w2 + 2) * 8 + ks) * 64 + ln];
    }
    for (int i = threadIdx.x; i < 2 * 16 * 264; i += 256)
        (&h_lds[0][0][0])[i] = (bf16_t)0.0f;           // h0 = 0

    f32x4 c0 = {0.f,0.f,0.f,0.f}, c1 = {0.f,0.f,0.f,0.f};
    f32x4 c2 = {0.f,0.f,0.f,0.f}, c3 = {0.f,0.f,0.f,0.f};

    bf16x4 xzv[4][4];   // [tile][gate], prefetched
#pragma unroll
    for (int T = 0; T < 4; T++)
#pragma unroll
        for (int G = 0; G < 4; G++)
            xzv[T][G] = xz2[((size_t)(0 * 4 + g) * 64 + (G * 16 + 4 * w + T)) * 64 + lane];

    __syncthreads();

    for (int t = 0; t < T_SZ; t++) {
        const int buf  = t & 1;
        const int nbuf = buf ^ 1;
        const bool last = (t == T_SZ - 1);

        asm volatile("" ::: "memory");   // inert: blocks cross-iter load hoist

        // ---- stream prologue: groups 0..3 = (G0,h0)(G0,h1)(G1,h0)(G1,h1) ---
        bf16x8 sgA[4][4];
#pragma unroll
        for (int k = 0; k < 4; k++) {
            int G = k >> 1, h = k & 1;
#pragma unroll
            for (int j = 0; j < 4; j++)
                sgA[k][j] = Uf[((G * 16 + ntS) * 8 + h * 4 + j) * 64];
        }
        __builtin_amdgcn_sched_barrier(0);

        // A-frags: h_t (shared by all 4 tiles)
        bf16x8 af[8];
#pragma unroll
        for (int ks = 0; ks < 8; ks++)
            af[ks] = *(const bf16x8*)&h_lds[buf][l15][ks * 32 + quad * 8];

        // accumulators from prefetched xz
        f32x4 a0[4], a1[4], a2[4], a3[4];
#pragma unroll
        for (int G = 0; G < 4; G++) {
            a0[G] = f32x4{(float)xzv[0][G][0], (float)xzv[0][G][1], (float)xzv[0][G][2], (float)xzv[0][G][3]};
            a1[G] = f32x4{(float)xzv[1][G][0], (float)xzv[1][G][1], (float)xzv[1][G][2], (float)xzv[1][G][3]};
            a2[G] = f32x4{(float)xzv[2][G][0], (float)xzv[2][G][1], (float)xzv[2][G][2], (float)xzv[2][G][3]};
            a3[G] = f32x4{(float)xzv[3][G][0], (float)xzv[3][G][1], (float)xzv[3][G][2], (float)xzv[3][G][3]};
        }

        // ---- tiles 4w, 4w+1: all-AGPR MFMAs (64) ---------------------------
#pragma unroll
        for (int ks = 0; ks < 8; ks++)
#pragma unroll
            for (int G = 0; G < 4; G++)
                mfma_aB(a0[G], af[ks], uA[0][G][ks]);
#pragma unroll
        for (int ks = 0; ks < 8; ks++)
#pragma unroll
            for (int G = 0; G < 4; G++)
                mfma_aB(a1[G], af[ks], uA[1][G][ks]);

        // prefetch next step's xz (xzv regs are dead after acc init)
        if (t + 1 < T_SZ) {
#pragma unroll
            for (int T = 0; T < 4; T++)
#pragma unroll
                for (int G = 0; G < 4; G++)
                    xzv[T][G] = xz2[((size_t)((t + 1) * 4 + g) * 64 + (G * 16 + 4 * w + T)) * 64 + lane];
        }

        // ---- gates for tiles 4w, 4w+1 --------------------------------------
        {
            float hv[4];
#pragma unroll
            for (int r = 0; r < 4; r++) {
                float ig = sigmoid_f(a0[0][r]), fg = sigmoid_f(a0[1][r]);
                float gg = tanh_f(a0[2][r]),    og = sigmoid_f(a0[3][r]);
                float cn = fg * c0[r] + ig * gg; c0[r] = cn;
                hv[r] = og * tanh_f(cn);
            }
            if (last) { for (int r = 0; r < 4; r++) hfin[(g*16+quad*4+r)*HID + (4*w)*16 + l15] = hv[r]; }
            else      { for (int r = 0; r < 4; r++) h_lds[nbuf][quad*4+r][(4*w)*16 + l15] = (bf16_t)hv[r]; }
#pragma unroll
            for (int r = 0; r < 4; r++) {
                float ig = sigmoid_f(a1[0][r]), fg = sigmoid_f(a1[1][r]);
                float gg = tanh_f(a1[2][r]),    og = sigmoid_f(a1[3][r]);
                float cn = fg * c1[r] + ig * gg; c1[r] = cn;
                hv[r] = og * tanh_f(cn);
            }
            if (last) { for (int r = 0; r < 4; r++) hfin[(g*16+quad*4+r)*HID + (4*w+1)*16 + l15] = hv[r]; }
            else      { for (int r = 0; r < 4; r++) h_lds[nbuf][quad*4+r][(4*w+1)*16 + l15] = (bf16_t)hv[r]; }
        }
        __builtin_amdgcn_sched_barrier(0);

        // ---- steady stream: consume sgA[k] (G=k>>1), issue sgB[k] (G2=2+…) -
        bf16x8 sgB[4][4];
#pragma unroll
        for (int k = 0; k < 4; k++) {
            int G = k >> 1, h = k & 1;
#pragma unroll
            for (int j = 0; j < 4; j++)
                a3[G] = __builtin_amdgcn_mfma_f32_16x16x32_bf16(af[h * 4 + j], sgA[k][j], a3[G], 0, 0, 0);
            int G2 = 2 + (k >> 1);
#pragma unroll
            for (int j = 0; j < 4; j++)
                sgB[k][j] = Uf[((G2 * 16 + ntS) * 8 + h * 4 + j) * 64];
            __builtin_amdgcn_sched_barrier(0);
        }

        // ---- tile 4w+2: LDS MFMAs (32) — gives sgB time to land -----------
        {
            const bf16x8* ub = ulds + ((unsigned)(w * 32) << 6) + lane;
#pragma unroll
            for (int ks = 0; ks < 8; ks++)
#pragma unroll
                for (int G = 0; G < 4; G++) {
                    bf16x8 bfrag = ub[(unsigned)((G * 8 + ks) << 6)];
                    a2[G] = __builtin_amdgcn_mfma_f32_16x16x32_bf16(af[ks], bfrag, a2[G], 0, 0, 0);
                }
        }
        __builtin_amdgcn_sched_barrier(0);

        // ---- consume sgB (gates G2,G3 of streamed tile) --------------------
#pragma unroll
        for (int k = 0; k < 4; k++) {
            int G2 = 2 + (k >> 1), h = k & 1;
#pragma unroll
            for (int j = 0; j < 4; j++)
                a3[G2] = __builtin_amdgcn_mfma_f32_16x16x32_bf16(af[h * 4 + j], sgB[k][j], a3[G2], 0, 0, 0);
        }

        // ---- gates for tiles 4w+2, 4w+3 ------------------------------------
        {
            float hv[4];
#pragma unroll
            for (int r = 0; r < 4; r++) {
                float ig = sigmoid_f(a2[0][r]), fg = sigmoid_f(a2[1][r]);
                float gg = tanh_f(a2[2][r]),    og = sigmoid_f(a2[3][r]);
                float cn = fg * c2[r] + ig * gg; c2[r] = cn;
                hv[r] = og * tanh_f(cn);
            }
            if (last) { for (int r = 0; r < 4; r++) hfin[(g*16+quad*4+r)*HID + (4*w+2)*16 + l15] = hv[r]; }
            else      { for (int r = 0; r < 4; r++) h_lds[nbuf][quad*4+r][(4*w+2)*16 + l15] = (bf16_t)hv[r]; }
#pragma unroll
            for (int r = 0; r < 4; r++) {
                float ig = sigmoid_f(a3[0][r]), fg = sigmoid_f(a3[1][r]);
                float gg = tanh_f(a3[2][r]),    og = sigmoid_f(a3[3][r]);
                float cn = fg * c3[r] + ig * gg; c3[r] = cn;
                hv[r] = og * tanh_f(cn);
            }
            if (last) { for (int r = 0; r < 4; r++) hfin[(g*16+quad*4+r)*HID + ntS*16 + l15] = hv[r]; }
            else      { for (int r = 0; r < 4; r++) h_lds[nbuf][quad*4+r][ntS*16 + l15] = (bf16_t)hv[r]; }
        }

        if (last) break;      // uniform exit
        __syncthreads();      // h_{t+1} complete in LDS
    }
}

// ---------------------------------------------------------------------------
// Phase C: logits = h_T @ Wd + bd; softmax. One block per batch row.
// ---------------------------------------------------------------------------
__global__ void head(const float* __restrict__ hfin, const float* __restrict__ Wd,
                     const float* __restrict__ bd, float* __restrict__ out) {
    __shared__ float hrow[HID];
    __shared__ float lg[32];
    __shared__ float ex[32];
    int b = blockIdx.x, tid = threadIdx.x;   // 64 threads
    for (int i = tid; i < HID; i += 64) hrow[i] = hfin[b * HID + i];
    __syncthreads();
    if (tid < NCLS) {
        float acc = bd[tid];
        for (int k = 0; k < HID; k++) acc = fmaf(hrow[k], Wd[k * NCLS + tid], acc);
        lg[tid] = acc;
    }
    __syncthreads();
    if (tid < NCLS) {
        float m = -1e30f;
        for (int jj = 0; jj < NCLS; jj++) m = fmaxf(m, lg[jj]);
        ex[tid] = __expf(lg[tid] - m);
    }
    __syncthreads();
    if (tid < NCLS) {
        float sden = 0.0f;
        for (int jj = 0; jj < NCLS; jj++) sden += ex[jj];
        out[b * NCLS + tid] = ex[tid] / sden;
    }
}

// ---------------------------------------------------------------------------
extern "C" void kernel_launch(void* const* d_in, const int* in_sizes, int n_in,
                              void* d_out, int out_size, void* d_ws, size_t ws_size,
                              hipStream_t stream) {
    const int*   x    = (const int*)d_in[0];
    const float* emb  = (const float*)d_in[1];
    const float* W    = (const float*)d_in[2];
    const float* U    = (const float*)d_in[3];
    const float* bias = (const float*)d_in[4];
    const float* Wd   = (const float*)d_in[5];
    const float* bd   = (const float*)d_in[6];
    float* out = (float*)d_out;

    char* ws = (char*)d_ws;
    bf16_t* Up  = (bf16_t*)(ws + WS_UPACK);
    bf16_t* Wp  = (bf16_t*)(ws + WS_WPACK);
    float*  hf  = (float*)(ws + WS_HFIN);
    bf16x4* xz2 = (bf16x4*)(ws + WS_XZ);

    pack_weights<<<dim3(1024), dim3(256), 0, stream>>>(W, U, Wp, Up);
    xz_gemm<<<dim3(4096), dim3(256), 0, stream>>>(x, emb, Wp, bias, xz2);
    lstm_v4<<<dim3(4), dim3(256), 0, stream>>>(xz2, Up, hf);
    head<<<dim3(64), dim3(64), 0, stream>>>(hf, Wd, bd, out);
}